// Round 10
// baseline (721.823 us; speedup 1.0000x reference)
//
#include <hip/hip_runtime.h>
#include <hip/hip_bf16.h>

#define T_LEN 512
#define HID 50
#define NBATCH 4096
#define BB 8          // batches per 128-thread (2-wave) block

using short8  = __attribute__((ext_vector_type(8))) short;
using floatx4 = __attribute__((ext_vector_type(4))) float;

__device__ __forceinline__ float sigm(float v) {
  return __builtin_amdgcn_rcpf(1.0f + __builtin_amdgcn_exp2f(-1.442695041f * v));
}
__device__ __forceinline__ float tanh_f(float v) {
  return 1.0f - 2.0f * __builtin_amdgcn_rcpf(1.0f + __builtin_amdgcn_exp2f(2.885390082f * v));
}
__device__ __forceinline__ unsigned short bf16hi(float v) {
  __hip_bfloat16 b = __float2bfloat16(v);
  return *(unsigned short*)&b;
}
__device__ __forceinline__ float bf16tof(unsigned short u) {
  return __uint_as_float((unsigned int)u << 16);
}

// h plane: 16 rows (m=batch, 0-7 real) x 64 bf16 cols, row 128 B, XOR ((m&7)<<4).
// Cols: 0..49 h_hi ; 50..52 x_hi ; 53 = 1.0 ; 54..56 x_lo ; 57..63 = 0.
// k-bijection (A reads and B build): k = 32*f + 8*kg + e.
__global__ __launch_bounds__(128, 1)
void gru_mfma_kernel(const float* __restrict__ x,
                     const float* __restrict__ W_ih,
                     const float* __restrict__ W_hh,
                     const float* __restrict__ b_ih,
                     const float* __restrict__ b_hh,
                     const float* __restrict__ W_fc,
                     const float* __restrict__ b_fc,
                     float* __restrict__ out) {
  // LDS: [0,6144) x-chunk [i64][c3][m8] f32 (i = t - (tc*64+1)) ; [6144,10240) 2 h planes
  __shared__ alignas(16) unsigned char lds[6144 + 4096];
  char* xs   = (char*)lds;
  char* hbuf = (char*)lds + 6144;

  const int tid  = threadIdx.x;
  const int lane = tid & 63;
  const int w    = tid >> 6;              // 0 or 1: owns units 32w..32w+31 (2 tiles)
  const int ucol = lane & 15;
  const int kg   = (lane >> 4) & 3;
  const int b0   = blockIdx.x * BB;

  const int u0 = 32 * w + ucol;           // tile 0 unit
  const int u1 = 32 * w + 16 + ucol;      // tile 1 unit
  const float wfc0 = (u0 < HID) ? W_fc[u0] : 0.f;
  const float wfc1 = (u1 < HID) ? W_fc[u1] : 0.f;

  // ---- augmented B fragments, per N-tile ----
  short8 Bh[2][3][2], Bl[2][3][2];        // [tile][gate r/z/nh][frag]
  short8 Bch[2], Bcl[2];                  // n-gate x-part (frag1 rows 50-56)
#pragma unroll
  for (int T = 0; T < 2; ++T) {
    const int u = 32 * w + 16 * T + ucol;
    const bool uv = (u < HID);
#pragma unroll
    for (int g = 0; g < 3; ++g) {
#pragma unroll
      for (int f = 0; f < 2; ++f) {
        union { short a[8]; short8 s; } ph, pl;
#pragma unroll
        for (int e = 0; e < 8; ++e) {
          const int k = 32 * f + 8 * kg + e;
          float v = 0.f;
          if (uv) {
            if (k < HID) v = W_hh[(g * 50 + u) * HID + k];
            else if (g < 2) {
              if (k <= 52)      v = W_ih[(g * 50 + u) * 3 + (k - 50)];
              else if (k == 53) v = b_ih[g * 50 + u] + b_hh[g * 50 + u];
              else if (k <= 56) v = W_ih[(g * 50 + u) * 3 + (k - 54)];
            } else {
              if (k == 53)      v = b_hh[100 + u];
            }
          }
          const unsigned short hi = bf16hi(v);
          const unsigned short lo = bf16hi(v - bf16tof(hi));
          ph.a[e] = (short)hi; pl.a[e] = (short)lo;
        }
        Bh[T][g][f] = ph.s; Bl[T][g][f] = pl.s;
      }
    }
    {
      union { short a[8]; short8 s; } ph, pl;
#pragma unroll
      for (int e = 0; e < 8; ++e) {
        const int k = 32 + 8 * kg + e;
        float v = 0.f;
        if (uv) {
          if (k >= 50 && k <= 52)      v = W_ih[(100 + u) * 3 + (k - 50)];
          else if (k == 53)            v = b_ih[100 + u];
          else if (k >= 54 && k <= 56) v = W_ih[(100 + u) * 3 + (k - 54)];
        }
        const unsigned short hi = bf16hi(v);
        const unsigned short lo = bf16hi(v - bf16tof(hi));
        ph.a[e] = (short)hi; pl.a[e] = (short)lo;
      }
      Bch[T] = ph.s; Bcl[T] = pl.s;
    }
  }

  // ---- init: zero both planes, seed x(0) + 1.0 into plane 0 (rows 0-7) ----
  ((float4*)hbuf)[tid]       = make_float4(0.f, 0.f, 0.f, 0.f);
  ((float4*)hbuf)[tid + 128] = make_float4(0.f, 0.f, 0.f, 0.f);
  __syncthreads();
  if (tid < 32) {
    const int m = tid & 7, c = tid >> 3;
    char* p0 = hbuf + m * 128;
    const int xr = m << 4;
    if (c == 3) {
      *(unsigned short*)(p0 + ((2 * 53) ^ xr)) = 0x3F80;
    } else {
      const float xv = x[(size_t)(b0 + m) * (T_LEN * 3) + c];
      const unsigned short hi = bf16hi(xv);
      *(unsigned short*)(p0 + ((2 * (50 + c)) ^ xr)) = hi;
      *(unsigned short*)(p0 + ((2 * (54 + c)) ^ xr)) = bf16hi(xv - bf16tof(hi));
    }
  }

  float h0[4] = {0.f, 0.f, 0.f, 0.f};
  float h1[4] = {0.f, 0.f, 0.f, 0.f};
  const int arow = ucol * 128;            // A row m = batch = lane&15
  const int axr  = (ucol & 7) << 4;
  const floatx4 z4 = {0.f, 0.f, 0.f, 0.f};

  // x-duty descriptors (wave 1, tile 1, cols 50-56); branch-free selects
  int xc = (ucol >= 6) ? (ucol - 6) : (ucol - 2);
  xc = xc < 0 ? 0 : (xc > 2 ? 2 : xc);
  const bool isOne = (ucol == 5);
  const bool isHi  = (ucol >= 2 && ucol <= 4);
  const bool isH1  = (ucol < 2);          // units 48,49 = real h

  for (int tc = 0; tc < 8; ++tc) {
    // ---- stage x for t = tc*64+1 .. +64 (i = 0..63), layout [i][c][m8] ----
    {
      const int sm = tid >> 4, seg = tid & 15;
      const float* xb = x + (size_t)(b0 + sm) * (T_LEN * 3) + tc * 192 + 3 + seg * 12;
      float vv[12];
      if (tc == 7 && seg == 15) {
#pragma unroll
        for (int j = 0; j < 12; ++j) vv[j] = (j < 9) ? xb[j] : 0.f;
      } else {
        const float4 v0 = *(const float4*)(xb + 0);
        const float4 v1 = *(const float4*)(xb + 4);
        const float4 v2 = *(const float4*)(xb + 8);
        vv[0]=v0.x; vv[1]=v0.y; vv[2]=v0.z; vv[3]=v0.w;
        vv[4]=v1.x; vv[5]=v1.y; vv[6]=v1.z; vv[7]=v1.w;
        vv[8]=v2.x; vv[9]=v2.y; vv[10]=v2.z; vv[11]=v2.w;
      }
#pragma unroll
      for (int jj = 0; jj < 12; ++jj) {
        const int i = seg * 12 + jj;
        *(float*)(xs + (i / 3) * 96 + (i % 3) * 32 + sm * 4) = vv[jj];
      }
    }
    __syncthreads();

#pragma unroll 2
    for (int s = 0; s < 64; ++s) {
      const int par = s & 1;
      const char* rp = hbuf + par * 2048;
      char*       wp = hbuf + (par ^ 1) * 2048;

      const short8 A0 = *(const short8*)(rp + arow + ((16 * kg)      ^ axr));
      const short8 A1 = *(const short8*)(rp + arow + ((16 * kg + 64) ^ axr));

      unsigned short hb0[4], hb1[4];
#pragma unroll
      for (int T = 0; T < 2; ++T) {
        // 2+2-deep parallel chains per gate (r8 structure)
        floatx4 r1 = __builtin_amdgcn_mfma_f32_16x16x32_bf16(A0, Bh[T][0][0], z4, 0, 0, 0);
        r1 = __builtin_amdgcn_mfma_f32_16x16x32_bf16(A1, Bh[T][0][1], r1, 0, 0, 0);
        floatx4 r2 = __builtin_amdgcn_mfma_f32_16x16x32_bf16(A0, Bl[T][0][0], z4, 0, 0, 0);
        r2 = __builtin_amdgcn_mfma_f32_16x16x32_bf16(A1, Bl[T][0][1], r2, 0, 0, 0);
        floatx4 zA = __builtin_amdgcn_mfma_f32_16x16x32_bf16(A0, Bh[T][1][0], z4, 0, 0, 0);
        zA = __builtin_amdgcn_mfma_f32_16x16x32_bf16(A1, Bh[T][1][1], zA, 0, 0, 0);
        floatx4 zB = __builtin_amdgcn_mfma_f32_16x16x32_bf16(A0, Bl[T][1][0], z4, 0, 0, 0);
        zB = __builtin_amdgcn_mfma_f32_16x16x32_bf16(A1, Bl[T][1][1], zB, 0, 0, 0);
        floatx4 nA = __builtin_amdgcn_mfma_f32_16x16x32_bf16(A0, Bh[T][2][0], z4, 0, 0, 0);
        nA = __builtin_amdgcn_mfma_f32_16x16x32_bf16(A1, Bh[T][2][1], nA, 0, 0, 0);
        floatx4 nB = __builtin_amdgcn_mfma_f32_16x16x32_bf16(A0, Bl[T][2][0], z4, 0, 0, 0);
        nB = __builtin_amdgcn_mfma_f32_16x16x32_bf16(A1, Bl[T][2][1], nB, 0, 0, 0);
        floatx4 cC = __builtin_amdgcn_mfma_f32_16x16x32_bf16(A1, Bch[T], z4, 0, 0, 0);
        cC = __builtin_amdgcn_mfma_f32_16x16x32_bf16(A1, Bcl[T], cC, 0, 0, 0);

        float*          hh = T ? h1  : h0;   // T is compile-time (unrolled)
        unsigned short* hb = T ? hb1 : hb0;
#pragma unroll
        for (int r = 0; r < 4; ++r) {
          const float rr = sigm(r1[r] + r2[r]);
          const float zz = sigm(zA[r] + zB[r]);
          const float nv = fmaf(rr, nA[r] + nB[r], cC[r]);
          const float nn = tanh_f(nv);
          hh[r] = fmaf(zz, hh[r] - nn, nn);
          hb[r] = bf16hi(hh[r]);
        }
      }

      if (kg < 2) {                          // rows 0-7 only
#pragma unroll
        for (int r = 0; r < 4; ++r) {
          const int m = 4 * kg + r;
          char* base = wp + m * 128;
          const int xr2 = m << 4;
          *(unsigned short*)(base + ((2 * u0) ^ xr2)) = hb0[r];
          if (w == 0) {
            *(unsigned short*)(base + ((2 * u1) ^ xr2)) = hb1[r];
          } else if (ucol < 9) {
            const float xv = *(const float*)(xs + s * 96 + xc * 32 + m * 4);
            const unsigned short hi = bf16hi(xv);
            const unsigned short lo = bf16hi(xv - bf16tof(hi));
            unsigned short val = isHi ? hi : lo;
            val = isOne ? (unsigned short)0x3F80 : val;
            val = isH1 ? hb1[r] : val;
            *(unsigned short*)(base + ((2 * u1) ^ xr2)) = val;
          }
        }
      }
      __syncthreads();
    }
  }

  // ---- FC epilogue: out[b] = sum_u h_u * W_fc[u] + b_fc ----
  __syncthreads();
  if (kg < 2) {
    float p[4];
#pragma unroll
    for (int r = 0; r < 4; ++r) p[r] = h0[r] * wfc0 + h1[r] * wfc1;
#pragma unroll
    for (int mask = 1; mask < 16; mask <<= 1) {
#pragma unroll
      for (int r = 0; r < 4; ++r) p[r] += __shfl_xor(p[r], mask);
    }
    if (ucol == 0) {
      *(float4*)((float*)lds + (w * 8 + kg * 4)) = make_float4(p[0], p[1], p[2], p[3]);
    }
  }
  __syncthreads();
  if (tid < BB) {
    out[b0 + tid] = ((const float*)lds)[tid] + ((const float*)lds)[8 + tid] + b_fc[0];
  }
}

extern "C" void kernel_launch(void* const* d_in, const int* in_sizes, int n_in,
                              void* d_out, int out_size, void* d_ws, size_t ws_size,
                              hipStream_t stream) {
  const float* x    = (const float*)d_in[0];
  const float* W_ih = (const float*)d_in[1];
  const float* W_hh = (const float*)d_in[2];
  const float* b_ih = (const float*)d_in[3];
  const float* b_hh = (const float*)d_in[4];
  const float* W_fc = (const float*)d_in[5];
  const float* b_fc = (const float*)d_in[6];
  float* out = (float*)d_out;

  dim3 grid(NBATCH / BB);   // 512 blocks x 128 threads: 2-wave exchange groups
  dim3 block(128);
  gru_mfma_kernel<<<grid, block, 0, stream>>>(x, W_ih, W_hh, b_ih, b_hh, W_fc, b_fc, out);
}

// Round 11
// 266.246 us; speedup vs baseline: 2.7111x; 2.7111x over previous
//
#include <hip/hip_runtime.h>
#include <hip/hip_bf16.h>

#define T_LEN 512
#define HID 50
#define NBATCH 4096

using short8  = __attribute__((ext_vector_type(8))) short;
using floatx4 = __attribute__((ext_vector_type(4))) float;

__device__ __forceinline__ float sigm(float v) {
  return __builtin_amdgcn_rcpf(1.0f + __builtin_amdgcn_exp2f(-1.442695041f * v));
}
__device__ __forceinline__ float tanh_f(float v) {
  return 1.0f - 2.0f * __builtin_amdgcn_rcpf(1.0f + __builtin_amdgcn_exp2f(2.885390082f * v));
}
__device__ __forceinline__ unsigned short bf16hi(float v) {
  __hip_bfloat16 b = __float2bfloat16(v);
  return *(unsigned short*)&b;
}
__device__ __forceinline__ float bf16tof(unsigned short u) {
  return __uint_as_float((unsigned int)u << 16);
}

// h plane: 16 rows (m=batch) x 64 bf16 cols, row = 128 B, XOR swizzle ((m&7)<<4).
// Cols: 0..49 h_hi ; 50..52 x_hi ; 53 = 1.0 ; 54..56 x_lo ; 57..63 = 0.
// k-bijection (A reads and B build): k = 32*f + 8*kg + e.
__global__ __launch_bounds__(256, 1)
void gru_mfma_kernel(const float* __restrict__ x,
                     const float* __restrict__ W_ih,
                     const float* __restrict__ W_hh,
                     const float* __restrict__ b_ih,
                     const float* __restrict__ b_hh,
                     const float* __restrict__ W_fc,
                     const float* __restrict__ b_fc,
                     float* __restrict__ out) {
  // LDS: [0,12288) x-chunk [i64][c3][m16] f32 (i = t-(tc*64+1)) ; [12288,16384) 2 h planes
  __shared__ alignas(16) unsigned char lds[16384];
  char* xs   = (char*)lds;
  char* hbuf = (char*)lds + 12288;

  const int tid  = threadIdx.x;
  const int lane = tid & 63;
  const int w    = tid >> 6;             // wave id: owns units 16w..16w+15
  const int ucol = lane & 15;            // N-col / A-row (batch) index
  const int kg   = (lane >> 4) & 3;
  const int b0   = blockIdx.x * 16;
  const int u    = 16 * w + ucol;
  const bool uv  = (u < HID);

  const float wfc = uv ? W_fc[u] : 0.f;

  // ---- augmented B fragments (built once) ----
  short8 Bh[3][2], Bl[3][2];   // gates 0=r, 1=z, 2=n(h-part, b_hn at k=53)
  short8 Bch, Bcl;             // n-gate x-part (frag1): W_in at 50..52/54..56, b_in at 53
#pragma unroll
  for (int g = 0; g < 3; ++g) {
#pragma unroll
    for (int f = 0; f < 2; ++f) {
      union { short a[8]; short8 s; } ph, pl;
#pragma unroll
      for (int e = 0; e < 8; ++e) {
        const int k = 32 * f + 8 * kg + e;
        float v = 0.f;
        if (uv) {
          if (k < HID) v = W_hh[(g * 50 + u) * HID + k];
          else if (g < 2) {
            if (k <= 52)      v = W_ih[(g * 50 + u) * 3 + (k - 50)];
            else if (k == 53) v = b_ih[g * 50 + u] + b_hh[g * 50 + u];
            else if (k <= 56) v = W_ih[(g * 50 + u) * 3 + (k - 54)];
          } else {
            if (k == 53)      v = b_hh[100 + u];
          }
        }
        const unsigned short hi = bf16hi(v);
        const unsigned short lo = bf16hi(v - bf16tof(hi));
        ph.a[e] = (short)hi; pl.a[e] = (short)lo;
      }
      Bh[g][f] = ph.s; Bl[g][f] = pl.s;
    }
  }
  {
    union { short a[8]; short8 s; } ph, pl;
#pragma unroll
    for (int e = 0; e < 8; ++e) {
      const int k = 32 + 8 * kg + e;
      float v = 0.f;
      if (uv) {
        if (k >= 50 && k <= 52)      v = W_ih[(100 + u) * 3 + (k - 50)];
        else if (k == 53)            v = b_ih[100 + u];
        else if (k >= 54 && k <= 56) v = W_ih[(100 + u) * 3 + (k - 54)];
      }
      const unsigned short hi = bf16hi(v);
      const unsigned short lo = bf16hi(v - bf16tof(hi));
      ph.a[e] = (short)hi; pl.a[e] = (short)lo;
    }
    Bch = ph.s; Bcl = pl.s;
  }

  // ---- init: zero both planes, seed x(0) + 1.0 into plane 0 ----
  ((float4*)hbuf)[tid] = make_float4(0.f, 0.f, 0.f, 0.f);
  __syncthreads();
  if (tid < 64) {
    const int m = tid & 15, c = tid >> 4;   // c = 0..3
    char* p0 = hbuf + m * 128;
    const int xr = (m & 7) << 4;
    if (c == 3) {
      *(unsigned short*)(p0 + ((2 * 53) ^ xr)) = 0x3F80;  // 1.0 bf16
    } else {
      const float xv = x[(size_t)(b0 + m) * (T_LEN * 3) + c];
      const unsigned short hi = bf16hi(xv);
      *(unsigned short*)(p0 + ((2 * (50 + c)) ^ xr)) = hi;
      *(unsigned short*)(p0 + ((2 * (54 + c)) ^ xr)) = bf16hi(xv - bf16tof(hi));
    }
  }

  float h[4] = {0.f, 0.f, 0.f, 0.f};
  const int arow = ucol * 128;
  const int axr  = (ucol & 7) << 4;
  const floatx4 z4 = {0.f, 0.f, 0.f, 0.f};

  // store offsets
  int hoff[4];
#pragma unroll
  for (int r = 0; r < 4; ++r) {
    const int m = 4 * kg + r;
    hoff[r] = m * 128 + ((2 * u) ^ ((m & 7) << 4));
  }
  // wave-3 x-duty (branch-free): ucol 2..4 -> x_hi(ucol-2) ; 5 -> 1.0 ; 6..8 -> x_lo(ucol-6)
  int xc = (ucol >= 6) ? (ucol - 6) : (ucol - 2);
  xc = xc < 0 ? 0 : (xc > 2 ? 2 : xc);
  const int xcol   = (ucol >= 6) ? (54 + xc) : (ucol == 5 ? 53 : 50 + xc);
  const bool isOne = (ucol == 5);
  const bool isHi  = (ucol >= 2 && ucol <= 4);
  const bool isH1  = (ucol < 2);          // units 48,49 = real h
  int soff[4], xroff[4];
#pragma unroll
  for (int r = 0; r < 4; ++r) {
    const int m = 4 * kg + r;
    soff[r]  = isH1 ? hoff[r] : (m * 128 + ((2 * xcol) ^ ((m & 7) << 4)));
    xroff[r] = xc * 64 + m * 4;
  }

  for (int tc = 0; tc < 8; ++tc) {
    // ---- stage x for t = tc*64+1 .. +64 (i = 0..63), layout [i][c][m16] ----
    {
      const int sm = tid >> 4, seg = tid & 15;
      const float* xb = x + (size_t)(b0 + sm) * (T_LEN * 3) + tc * 192 + 3 + seg * 12;
      float vv[12];
      if (tc == 7 && seg == 15) {
#pragma unroll
        for (int j = 0; j < 12; ++j) vv[j] = (j < 9) ? xb[j] : 0.f;  // t=512 pad
      } else {
        const float4 v0 = *(const float4*)(xb + 0);
        const float4 v1 = *(const float4*)(xb + 4);
        const float4 v2 = *(const float4*)(xb + 8);
        vv[0]=v0.x; vv[1]=v0.y; vv[2]=v0.z; vv[3]=v0.w;
        vv[4]=v1.x; vv[5]=v1.y; vv[6]=v1.z; vv[7]=v1.w;
        vv[8]=v2.x; vv[9]=v2.y; vv[10]=v2.z; vv[11]=v2.w;
      }
#pragma unroll
      for (int jj = 0; jj < 12; ++jj) {
        const int i = seg * 12 + jj;
        *(float*)(xs + (i / 3) * 192 + (i % 3) * 64 + sm * 4) = vv[jj];
      }
    }
    __syncthreads();

#pragma unroll 2
    for (int s = 0; s < 64; ++s) {
      const int par = s & 1;
      const char* rp = hbuf + par * 2048;
      char*       wp = hbuf + (par ^ 1) * 2048;

      const short8 A0 = *(const short8*)(rp + arow + ((16 * kg)      ^ axr));
      const short8 A1 = *(const short8*)(rp + arow + ((16 * kg + 64) ^ axr));

      // 2+2-deep parallel chains per gate (r8 schedule, r9 semantics)
      floatx4 r1 = __builtin_amdgcn_mfma_f32_16x16x32_bf16(A0, Bh[0][0], z4, 0, 0, 0);
      r1 = __builtin_amdgcn_mfma_f32_16x16x32_bf16(A1, Bh[0][1], r1, 0, 0, 0);
      floatx4 r2 = __builtin_amdgcn_mfma_f32_16x16x32_bf16(A0, Bl[0][0], z4, 0, 0, 0);
      r2 = __builtin_amdgcn_mfma_f32_16x16x32_bf16(A1, Bl[0][1], r2, 0, 0, 0);
      floatx4 zA = __builtin_amdgcn_mfma_f32_16x16x32_bf16(A0, Bh[1][0], z4, 0, 0, 0);
      zA = __builtin_amdgcn_mfma_f32_16x16x32_bf16(A1, Bh[1][1], zA, 0, 0, 0);
      floatx4 zB = __builtin_amdgcn_mfma_f32_16x16x32_bf16(A0, Bl[1][0], z4, 0, 0, 0);
      zB = __builtin_amdgcn_mfma_f32_16x16x32_bf16(A1, Bl[1][1], zB, 0, 0, 0);
      floatx4 nA = __builtin_amdgcn_mfma_f32_16x16x32_bf16(A0, Bh[2][0], z4, 0, 0, 0);
      nA = __builtin_amdgcn_mfma_f32_16x16x32_bf16(A1, Bh[2][1], nA, 0, 0, 0);
      floatx4 nB = __builtin_amdgcn_mfma_f32_16x16x32_bf16(A0, Bl[2][0], z4, 0, 0, 0);
      nB = __builtin_amdgcn_mfma_f32_16x16x32_bf16(A1, Bl[2][1], nB, 0, 0, 0);
      floatx4 c1 = __builtin_amdgcn_mfma_f32_16x16x32_bf16(A1, Bch, z4, 0, 0, 0);
      floatx4 c2 = __builtin_amdgcn_mfma_f32_16x16x32_bf16(A1, Bcl, c1, 0, 0, 0);

      unsigned short hb[4];
#pragma unroll
      for (int r = 0; r < 4; ++r) {
        const float rr = sigm(r1[r] + r2[r]);
        const float zz = sigm(zA[r] + zB[r]);
        const float nv = fmaf(rr, nA[r] + nB[r], c2[r]);
        const float nn = tanh_f(nv);
        h[r] = fmaf(zz, h[r] - nn, nn);
        hb[r] = bf16hi(h[r]);
      }

      if (w < 3) {                           // wave-uniform branch
#pragma unroll
        for (int r = 0; r < 4; ++r)
          *(unsigned short*)(wp + hoff[r]) = hb[r];
      } else {
        // branch-free value select; one predicated store per r
#pragma unroll
        for (int r = 0; r < 4; ++r) {
          const float xv = *(const float*)(xs + s * 192 + xroff[r]);
          const unsigned short hi = bf16hi(xv);
          const unsigned short lo = bf16hi(xv - bf16tof(hi));
          unsigned short val = isHi ? hi : lo;
          val = isOne ? (unsigned short)0x3F80 : val;
          val = isH1 ? hb[r] : val;
          if (ucol <= 8)
            *(unsigned short*)(wp + soff[r]) = val;
        }
      }
      __syncthreads();
    }
  }

  // ---- FC epilogue ----
  float p[4];
#pragma unroll
  for (int r = 0; r < 4; ++r) p[r] = h[r] * wfc;
#pragma unroll
  for (int mask = 1; mask < 16; mask <<= 1) {
#pragma unroll
    for (int r = 0; r < 4; ++r) p[r] += __shfl_xor(p[r], mask);
  }
  if (ucol == 0) {
    *(float4*)(lds + (w * 16 + 4 * kg) * 4) = make_float4(p[0], p[1], p[2], p[3]);
  }
  __syncthreads();
  if (tid < 16) {
    float ssum = 0.f;
#pragma unroll
    for (int ww = 0; ww < 4; ++ww) ssum += *(const float*)(lds + (ww * 16 + tid) * 4);
    out[b0 + tid] = ssum + b_fc[0];
  }
}

extern "C" void kernel_launch(void* const* d_in, const int* in_sizes, int n_in,
                              void* d_out, int out_size, void* d_ws, size_t ws_size,
                              hipStream_t stream) {
  const float* x    = (const float*)d_in[0];
  const float* W_ih = (const float*)d_in[1];
  const float* W_hh = (const float*)d_in[2];
  const float* b_ih = (const float*)d_in[3];
  const float* b_hh = (const float*)d_in[4];
  const float* W_fc = (const float*)d_in[5];
  const float* b_fc = (const float*)d_in[6];
  float* out = (float*)d_out;

  dim3 grid(NBATCH / 16);   // 256 blocks x 16 batches; 4 waves = 4 unit-tiles
  dim3 block(256);
  gru_mfma_kernel<<<grid, block, 0, stream>>>(x, W_ih, W_hh, b_ih, b_hh, W_fc, b_fc, out);
}